// Round 1
// baseline (1853.878 us; speedup 1.0000x reference)
//
#include <hip/hip_runtime.h>
#include <hip/hip_bf16.h>

#define N_NODES 100000
#define N_EDGES 1600000
#define D 64

// ---------------------------------------------------------------------------
// Phase 1: scatter  agg[dst] += x[src] * w_e
// 16 threads per edge; each thread handles one float4 (4 features).
// Consecutive threads of a wave touch consecutive float4s of the same row
// -> coalesced 256B gather per edge.
// ---------------------------------------------------------------------------
__global__ __launch_bounds__(256) void scatter_kernel(
    const float* __restrict__ x,
    const int* __restrict__ src,
    const int* __restrict__ dst,
    const float* __restrict__ w,
    float* __restrict__ agg)
{
    long long gid = (long long)blockIdx.x * blockDim.x + threadIdx.x;
    int e = (int)(gid >> 4);      // edge index
    int q = (int)(gid & 15);      // float4 slot within the 64-wide row
    if (e >= N_EDGES) return;

    int s = src[e];
    int d = dst[e];
    float we = w[e];

    const float4 xv = ((const float4*)(x + (size_t)s * D))[q];
    float* ap = agg + (size_t)d * D + q * 4;
    atomicAdd(ap + 0, xv.x * we);
    atomicAdd(ap + 1, xv.y * we);
    atomicAdd(ap + 2, xv.z * we);
    atomicAdd(ap + 3, xv.w * we);
}

// ---------------------------------------------------------------------------
// Phase 2: out = relu(agg @ W_rel^T + b_rel + x @ W_root^T)
// One wave per node, lane = output feature. Weights staged TRANSPOSED in LDS
// (lane o reads sW[d*64+o] -> consecutive addresses -> conflict-free).
// ---------------------------------------------------------------------------
__global__ __launch_bounds__(256) void linear_kernel(
    const float* __restrict__ x,
    const float* __restrict__ agg,
    const float* __restrict__ Wrel,
    const float* __restrict__ brel,
    const float* __restrict__ Wroot,
    float* __restrict__ out)
{
    __shared__ float sWrel[D * D];
    __shared__ float sWroot[D * D];

    int tid = threadIdx.x;
    // Load W[o][d] -> s[d*64 + o] (transpose).
    for (int i = tid; i < D * D; i += 256) {
        int o = i >> 6;
        int d = i & 63;
        sWrel[d * D + o]  = Wrel[i];
        sWroot[d * D + o] = Wroot[i];
    }
    __syncthreads();

    int wave = tid >> 6;
    int lane = tid & 63;
    int node = blockIdx.x * 4 + wave;
    if (node >= N_NODES) return;

    const float* ar = agg + (size_t)node * D;
    const float* xr = x   + (size_t)node * D;

    float acc = brel[lane];
#pragma unroll
    for (int d4 = 0; d4 < D; d4 += 4) {
        float4 av = *(const float4*)(ar + d4);
        float4 xv = *(const float4*)(xr + d4);
        acc += av.x * sWrel[(d4 + 0) * D + lane] + xv.x * sWroot[(d4 + 0) * D + lane];
        acc += av.y * sWrel[(d4 + 1) * D + lane] + xv.y * sWroot[(d4 + 1) * D + lane];
        acc += av.z * sWrel[(d4 + 2) * D + lane] + xv.z * sWroot[(d4 + 2) * D + lane];
        acc += av.w * sWrel[(d4 + 3) * D + lane] + xv.w * sWroot[(d4 + 3) * D + lane];
    }
    out[(size_t)node * D + lane] = fmaxf(acc, 0.0f);
}

extern "C" void kernel_launch(void* const* d_in, const int* in_sizes, int n_in,
                              void* d_out, int out_size, void* d_ws, size_t ws_size,
                              hipStream_t stream)
{
    const float* x     = (const float*)d_in[0];
    const int*   eidx  = (const int*)d_in[1];   // [2, E] -> row0 = src, row1 = dst
    const float* eattr = (const float*)d_in[2];
    const float* Wrel  = (const float*)d_in[3];
    const float* brel  = (const float*)d_in[4];
    const float* Wroot = (const float*)d_in[5];
    float* out = (float*)d_out;

    const int* src = eidx;
    const int* dst = eidx + N_EDGES;

    float* agg = (float*)d_ws;  // N * 64 floats = 25.6 MB

    // agg must be zeroed every call (d_ws is poisoned with 0xAA).
    hipMemsetAsync(agg, 0, (size_t)N_NODES * D * sizeof(float), stream);

    {
        long long total = (long long)N_EDGES * 16;
        int blocks = (int)((total + 255) / 256);
        scatter_kernel<<<blocks, 256, 0, stream>>>(x, src, dst, eattr, agg);
    }
    {
        int blocks = (N_NODES + 3) / 4;
        linear_kernel<<<blocks, 256, 0, stream>>>(x, agg, Wrel, brel, Wroot, out);
    }
}

// Round 2
// 455.727 us; speedup vs baseline: 4.0680x; 4.0680x over previous
//
#include <hip/hip_runtime.h>
#include <hip/hip_bf16.h>

#define N_NODES 100000
#define N_EDGES 1600000
#define D 64

#define SCAN_CHUNK 512
#define NCHUNKS ((N_NODES + SCAN_CHUNK - 1) / SCAN_CHUNK)   // 196

// ---------------------------------------------------------------------------
// 1. Degree histogram (int atomics — cheap, unlike fp32 atomics).
// ---------------------------------------------------------------------------
__global__ __launch_bounds__(256) void hist_kernel(const int* __restrict__ dst,
                                                   int* __restrict__ deg) {
    int e = blockIdx.x * 256 + threadIdx.x;
    if (e < N_EDGES) atomicAdd(&deg[dst[e]], 1);
}

// ---------------------------------------------------------------------------
// 2a. Per-chunk sums (chunk = 512 nodes).
// ---------------------------------------------------------------------------
__global__ __launch_bounds__(256) void chunk_sum_kernel(const int* __restrict__ deg,
                                                        int* __restrict__ bsum) {
    __shared__ int s[256];
    int b = blockIdx.x, t = threadIdx.x;
    int i0 = b * SCAN_CHUNK + t * 2;
    int v = 0;
    if (i0 < N_NODES)     v += deg[i0];
    if (i0 + 1 < N_NODES) v += deg[i0 + 1];
    s[t] = v;
    __syncthreads();
    for (int st = 128; st > 0; st >>= 1) {
        if (t < st) s[t] += s[t + st];
        __syncthreads();
    }
    if (t == 0) bsum[b] = s[0];
}

// ---------------------------------------------------------------------------
// 2b. Exclusive scan of the 196 chunk sums (single block, Hillis-Steele).
// ---------------------------------------------------------------------------
__global__ __launch_bounds__(256) void scan_blocks_kernel(const int* __restrict__ bsum,
                                                          int* __restrict__ bpref) {
    __shared__ int s[256];
    int t = threadIdx.x;
    int v = (t < NCHUNKS) ? bsum[t] : 0;
    s[t] = v;
    __syncthreads();
    for (int st = 1; st < 256; st <<= 1) {
        int add = (t >= st) ? s[t - st] : 0;
        __syncthreads();
        s[t] += add;
        __syncthreads();
    }
    if (t < NCHUNKS) bpref[t] = s[t] - v;   // exclusive
}

// ---------------------------------------------------------------------------
// 2c. Per-chunk exclusive scan + chunk prefix -> offsets (and cursor copy).
// ---------------------------------------------------------------------------
__global__ __launch_bounds__(256) void scan_chunk_kernel(const int* __restrict__ deg,
                                                         const int* __restrict__ bpref,
                                                         int* __restrict__ offsets,
                                                         int* __restrict__ cursor) {
    __shared__ int s[256];
    int b = blockIdx.x, t = threadIdx.x;
    int base = b * SCAN_CHUNK + t * 2;
    int a0 = (base < N_NODES) ? deg[base] : 0;
    int a1 = (base + 1 < N_NODES) ? deg[base + 1] : 0;
    int pair = a0 + a1;
    s[t] = pair;
    __syncthreads();
    for (int st = 1; st < 256; st <<= 1) {
        int add = (t >= st) ? s[t - st] : 0;
        __syncthreads();
        s[t] += add;
        __syncthreads();
    }
    int excl = s[t] - pair + bpref[b];
    if (base < N_NODES)     { offsets[base]     = excl;      cursor[base]     = excl; }
    if (base + 1 < N_NODES) { offsets[base + 1] = excl + a0; cursor[base + 1] = excl + a0; }
}

// ---------------------------------------------------------------------------
// 3. CSR fill: slot = fetch-add on per-node cursor.
// ---------------------------------------------------------------------------
__global__ __launch_bounds__(256) void fill_kernel(const int* __restrict__ src,
                                                   const int* __restrict__ dst,
                                                   const float* __restrict__ w,
                                                   int* __restrict__ cursor,
                                                   int* __restrict__ csr_src,
                                                   float* __restrict__ csr_w) {
    int e = blockIdx.x * 256 + threadIdx.x;
    if (e >= N_EDGES) return;
    int d = dst[e];
    int p = atomicAdd(&cursor[d], 1);
    csr_src[p] = src[e];
    csr_w[p]   = w[e];
}

// ---------------------------------------------------------------------------
// 4. Fused gather + linear.
//    Gather: one wave per node (lane = feature), 4 nodes per wave per round,
//    16 nodes staged in LDS. Linear: 16 threads per node, each does 4 outputs
//    via float4 LDS reads of transposed weights (ld=68: float4-aligned,
//    hot-loop bank-conflict-free).
// ---------------------------------------------------------------------------
#define WLD 68          // padded leading dim for weight / row staging
#define NPB 32          // nodes per block (2 rounds of 16)

__global__ __launch_bounds__(256) void gather_linear_kernel(
    const float* __restrict__ x,
    const int* __restrict__ offsets,
    const int* __restrict__ deg,
    const int* __restrict__ csr_src,
    const float* __restrict__ csr_w,
    const float* __restrict__ Wrel,
    const float* __restrict__ brel,
    const float* __restrict__ Wroot,
    float* __restrict__ out)
{
    __shared__ float sWrel[D * WLD];    // [d][o], transposed
    __shared__ float sWroot[D * WLD];
    __shared__ float sAgg[16][WLD];
    __shared__ float sX[16][WLD];
    __shared__ float sB[D];

    int tid = threadIdx.x;
    // Stage weights transposed: W[o][d] -> sW[d*WLD + o].
    for (int i = tid; i < D * D; i += 256) {
        int o = i >> 6, d = i & 63;
        sWrel[d * WLD + o]  = Wrel[i];
        sWroot[d * WLD + o] = Wroot[i];
    }
    if (tid < D) sB[tid] = brel[tid];
    __syncthreads();

    int wave = tid >> 6, lane = tid & 63;
    int base = blockIdx.x * NPB;

    for (int it = 0; it < NPB / 16; ++it) {
        // ---- gather phase: wave handles 4 nodes sequentially ----
        for (int k = 0; k < 4; ++k) {
            int nl = wave * 4 + k;
            int node = base + it * 16 + nl;
            float acc = 0.f, xv = 0.f;
            if (node < N_NODES) {
                xv = x[(size_t)node * D + lane];
                int off = offsets[node];
                int end = off + deg[node];
                int j = off;
                for (; j + 4 <= end; j += 4) {
                    int s0 = csr_src[j], s1 = csr_src[j + 1];
                    int s2 = csr_src[j + 2], s3 = csr_src[j + 3];
                    float w0 = csr_w[j], w1 = csr_w[j + 1];
                    float w2 = csr_w[j + 2], w3 = csr_w[j + 3];
                    acc += x[(size_t)s0 * D + lane] * w0;
                    acc += x[(size_t)s1 * D + lane] * w1;
                    acc += x[(size_t)s2 * D + lane] * w2;
                    acc += x[(size_t)s3 * D + lane] * w3;
                }
                for (; j < end; ++j)
                    acc += x[(size_t)csr_src[j] * D + lane] * csr_w[j];
            }
            sAgg[nl][lane] = acc;
            sX[nl][lane]   = xv;
        }
        __syncthreads();

        // ---- linear phase: 16 threads per node, 4 outputs each ----
        int nl = tid >> 4;             // 0..15
        int oq = (tid & 15) * 4;       // output quad start
        int node = base + it * 16 + nl;
        if (node < N_NODES) {
            float4 acc;
            acc.x = sB[oq]; acc.y = sB[oq + 1]; acc.z = sB[oq + 2]; acc.w = sB[oq + 3];
#pragma unroll 8
            for (int d = 0; d < D; ++d) {
                float a  = sAgg[nl][d];
                float xr = sX[nl][d];
                float4 wr = *(const float4*)&sWrel[d * WLD + oq];
                float4 wo = *(const float4*)&sWroot[d * WLD + oq];
                acc.x += a * wr.x + xr * wo.x;
                acc.y += a * wr.y + xr * wo.y;
                acc.z += a * wr.z + xr * wo.z;
                acc.w += a * wr.w + xr * wo.w;
            }
            float4 res;
            res.x = fmaxf(acc.x, 0.f); res.y = fmaxf(acc.y, 0.f);
            res.z = fmaxf(acc.z, 0.f); res.w = fmaxf(acc.w, 0.f);
            *(float4*)&out[(size_t)node * D + oq] = res;
        }
        __syncthreads();
    }
}

extern "C" void kernel_launch(void* const* d_in, const int* in_sizes, int n_in,
                              void* d_out, int out_size, void* d_ws, size_t ws_size,
                              hipStream_t stream)
{
    const float* x     = (const float*)d_in[0];
    const int*   eidx  = (const int*)d_in[1];
    const float* eattr = (const float*)d_in[2];
    const float* Wrel  = (const float*)d_in[3];
    const float* brel  = (const float*)d_in[4];
    const float* Wroot = (const float*)d_in[5];
    float* out = (float*)d_out;

    const int* src = eidx;
    const int* dst = eidx + N_EDGES;

    // Workspace layout (~14 MB).
    int*   deg     = (int*)d_ws;
    int*   offsets = deg + N_NODES;
    int*   cursor  = offsets + N_NODES;
    int*   bsum    = cursor + N_NODES;
    int*   bpref   = bsum + 256;
    int*   csr_src = bpref + 256;
    float* csr_w   = (float*)(csr_src + N_EDGES);

    hipMemsetAsync(deg, 0, N_NODES * sizeof(int), stream);

    hist_kernel<<<(N_EDGES + 255) / 256, 256, 0, stream>>>(dst, deg);
    chunk_sum_kernel<<<NCHUNKS, 256, 0, stream>>>(deg, bsum);
    scan_blocks_kernel<<<1, 256, 0, stream>>>(bsum, bpref);
    scan_chunk_kernel<<<NCHUNKS, 256, 0, stream>>>(deg, bpref, offsets, cursor);
    fill_kernel<<<(N_EDGES + 255) / 256, 256, 0, stream>>>(src, dst, eattr, cursor,
                                                           csr_src, csr_w);
    gather_linear_kernel<<<(N_NODES + NPB - 1) / NPB, 256, 0, stream>>>(
        x, offsets, deg, csr_src, csr_w, Wrel, brel, Wroot, out);
}